// Round 6
// baseline (775.275 us; speedup 1.0000x reference)
//
#include <hip/hip_runtime.h>

namespace {
constexpr int   NGRID  = 512;
constexpr int   NCELL  = NGRID * NGRID;
constexpr float DX     = 1.0f / (float)NGRID;
constexpr float INV_DX = (float)NGRID;
constexpr float DT     = 1e-4f;
constexpr float P_VOL  = (DX * 0.5f) * (DX * 0.5f);
constexpr float P_MASS = P_VOL * 1.0f;   // p_rho = 1
constexpr float GRAV   = 10.0f;

constexpr int TILE  = 16;            // cells per tile side
constexpr int TPR   = NGRID / TILE;  // 32 tiles per row
constexpr int NTILE = TPR * TPR;     // 1024
constexpr int REG   = TILE + 3;      // 19: region rows r0-1 .. r0+17
constexpr int RCELL = REG * REG;     // 361
constexpr int NBLK  = 512;           // blocks for count/scatter
constexpr int BLK   = 256;
constexpr int PBLK  = 512;           // threads for p2g_tile
}

// Native LDS fp32 atomic add (no return). hipcc lowers atomicAdd(float*) in
// LDS to a CAS loop (~200-400 cyc serialized, round-3 evidence); ds_add_f32
// is the HW path. Fire-and-forget: increments lgkmcnt, and the compiler's
// waitcnt pass does NOT track inline-asm DS ops, so the user MUST issue
// s_waitcnt lgkmcnt(0) before any barrier that precedes readback (round-5
// failure: lost contributions when waves crossed the barrier with adds still
// in flight).
__device__ __forceinline__ void lds_fadd(float* p, float v) {
    unsigned off = (unsigned)(uintptr_t)p;
    asm volatile("ds_add_f32 %0, %1" :: "v"(off), "v"(v) : "memory");
}
__device__ __forceinline__ void lds_drain() {
    asm volatile("s_waitcnt lgkmcnt(0)" ::: "memory");
}
// Round-4 lesson: hand-rolled global_atomic_add_f32 (no scope flags) is not
// safe across XCDs; use compiler atomicAdd for global halo adds.

// ---------------------------------------------------------------- count ----
__global__ __launch_bounds__(256) void k_count(
    const float2* __restrict__ x, int n, int ppb,
    int* __restrict__ cnt /* [NBLK][NTILE] */)
{
    __shared__ int hist[NTILE];
    for (int t = threadIdx.x; t < NTILE; t += BLK) hist[t] = 0;
    __syncthreads();
    const int b0 = blockIdx.x * ppb;
    const int b1 = min(b0 + ppb, n);
    for (int p = b0 + threadIdx.x; p < b1; p += BLK) {
        const float2 xp = x[p];
        const int ci = (int)(xp.x * INV_DX);
        const int cj = (int)(xp.y * INV_DX);
        atomicAdd(&hist[(ci >> 4) * TPR + (cj >> 4)], 1);   // int: native ds_add
    }
    __syncthreads();
    int* row = cnt + (size_t)blockIdx.x * NTILE;
    for (int t = threadIdx.x; t < NTILE; t += BLK) row[t] = hist[t];
}

// ----------------------------------------------------------------- scan ----
__global__ __launch_bounds__(1024) void k_scan(
    int* __restrict__ cnt, int* __restrict__ tile_start, int* __restrict__ tile_end)
{
    const int t = threadIdx.x;
    int s = 0;
    #pragma unroll 8
    for (int b = 0; b < NBLK; ++b) s += cnt[(size_t)b * NTILE + t];

    __shared__ int wsum[16];
    const int lane = t & 63, w = t >> 6;
    int inc = s;
    #pragma unroll
    for (int d = 1; d < 64; d <<= 1) {
        int u = __shfl_up(inc, d, 64);
        if (lane >= d) inc += u;
    }
    if (lane == 63) wsum[w] = inc;
    __syncthreads();
    if (t == 0) {
        int r = 0;
        #pragma unroll
        for (int i = 0; i < 16; ++i) { int v = wsum[i]; wsum[i] = r; r += v; }
    }
    __syncthreads();
    const int base = wsum[w] + inc - s;
    tile_start[t] = base;
    tile_end[t]   = base + s;

    int run = base;
    #pragma unroll 8
    for (int b = 0; b < NBLK; ++b) {
        int v = cnt[(size_t)b * NTILE + t];
        cnt[(size_t)b * NTILE + t] = run;
        run += v;
    }
}

// -------------------------------------------------------------- scatter ----
__global__ __launch_bounds__(256) void k_scatter(
    const float2* __restrict__ x,
    const float2* __restrict__ v,
    const float4* __restrict__ C,
    const float4* __restrict__ F,
    const int*    __restrict__ material,
    const float*  __restrict__ Jp,
    const float*  __restrict__ Ep,
    const float*  __restrict__ nup,
    int n, int ppb,
    const int* __restrict__ cnt,
    float4* __restrict__ packed,
    float4* __restrict__ outF,
    float*  __restrict__ outMat,
    float*  __restrict__ outJp)
{
    __shared__ int cur[NTILE];
    {
        const int* row = cnt + (size_t)blockIdx.x * NTILE;
        for (int t = threadIdx.x; t < NTILE; t += BLK) cur[t] = row[t];
    }
    __syncthreads();

    const float E  = Ep[0];
    const float nu = nup[0];
    const float mu0 = E / (2.0f * (1.0f + nu));
    const float la0 = E * nu / ((1.0f + nu) * (1.0f - 2.0f * nu));

    const int b0 = blockIdx.x * ppb;
    const int b1 = min(b0 + ppb, n);
    for (int p = b0 + threadIdx.x; p < b1; p += BLK) {
        const float2 xp = x[p];
        const float2 vp = v[p];
        const float4 c4 = C[p];
        const float4 f4 = F[p];
        const float  jp = Jp[p];

        const float F00 = f4.x + DT * (c4.x * f4.x + c4.y * f4.z);
        const float F01 = f4.y + DT * (c4.x * f4.y + c4.y * f4.w);
        const float F10 = f4.z + DT * (c4.z * f4.x + c4.w * f4.z);
        const float F11 = f4.w + DT * (c4.z * f4.y + c4.w * f4.w);

        const float h  = expf(10.0f * (1.0f - jp));
        const float mu = mu0 * h;
        const float la = la0 * h;

        const float a = F00 + F11;
        const float b = F10 - F01;
        const float r = sqrtf(a * a + b * b);
        const float cth = a / r;
        const float sth = b / r;
        const float J = fabsf(F00 * F11 - F01 * F10);

        const float A00 = F00 - cth, A01 = F01 + sth;
        const float A10 = F10 - sth, A11 = F11 - cth;
        const float PF00 = A00 * F00 + A01 * F01;
        const float PF01 = A00 * F10 + A01 * F11;
        const float PF10 = A10 * F00 + A11 * F01;
        const float PF11 = A10 * F10 + A11 * F11;

        constexpr float SC = -DT * P_VOL * 4.0f * INV_DX * INV_DX;
        const float diag = la * J * (J - 1.0f);
        const float twomu = 2.0f * mu;
        const float Af00 = SC * (twomu * PF00 + diag) + P_MASS * c4.x;
        const float Af01 = SC * (twomu * PF01)        + P_MASS * c4.y;
        const float Af10 = SC * (twomu * PF10)        + P_MASS * c4.z;
        const float Af11 = SC * (twomu * PF11 + diag) + P_MASS * c4.w;

        const int ci = (int)(xp.x * INV_DX);
        const int cj = (int)(xp.y * INV_DX);
        const int t  = (ci >> 4) * TPR + (cj >> 4);
        const int slot = atomicAdd(&cur[t], 1);      // int LDS atomic: native

        packed[2 * (size_t)slot]     = make_float4(xp.x, xp.y, P_MASS * vp.x, P_MASS * vp.y);
        packed[2 * (size_t)slot + 1] = make_float4(Af00, Af01, Af10, Af11);

        outF[p]   = make_float4(F00, F01, F10, F11);
        outMat[p] = (float)material[p];
        outJp[p]  = jp;
    }
}

// ------------------------------------------------------------- p2g tile ----
__global__ __launch_bounds__(PBLK) void k_p2g_tile(
    const float4* __restrict__ packed,
    const int* __restrict__ tile_start,
    const int* __restrict__ tile_end,
    float* __restrict__ gvx, float* __restrict__ gvy, float* __restrict__ gm)
{
    const int t  = blockIdx.x;
    const int s0 = tile_start[t];
    const int s1 = tile_end[t];
    if (s0 == s1) return;                       // uniform: safe before barriers

    __shared__ float acc[RCELL * 3];
    for (int i = threadIdx.x; i < RCELL * 3; i += PBLK) acc[i] = 0.0f;
    __syncthreads();

    const int tr = t >> 5, tc = t & 31;         // TPR = 32
    const int r0 = tr * TILE - 1, c0 = tc * TILE - 1;

    for (int p = s0 + threadIdx.x; p < s1; p += PBLK) {
        const float4 pa = packed[2 * (size_t)p];
        const float4 pb = packed[2 * (size_t)p + 1];
        const float xs = pa.x * INV_DX, ys = pa.y * INV_DX;
        const int bi = (int)(xs - 0.5f);
        const int bj = (int)(ys - 0.5f);
        const float fxx = xs - (float)bi;
        const float fxy = ys - (float)bj;

        float wx[3], wy[3];
        { float t0 = 1.5f - fxx, t1 = fxx - 1.0f, t2 = fxx - 0.5f;
          wx[0] = 0.5f * t0 * t0; wx[1] = 0.75f - t1 * t1; wx[2] = 0.5f * t2 * t2; }
        { float t0 = 1.5f - fxy, t1 = fxy - 1.0f, t2 = fxy - 0.5f;
          wy[0] = 0.5f * t0 * t0; wy[1] = 0.75f - t1 * t1; wy[2] = 0.5f * t2 * t2; }

        const int li = bi - r0;                 // 0..16
        const int lj = bj - c0;

        #pragma unroll
        for (int i = 0; i < 3; ++i) {
            const float dpx = ((float)i - fxx) * DX;
            #pragma unroll
            for (int j = 0; j < 3; ++j) {
                const float wgt = wx[i] * wy[j];
                const float dpy = ((float)j - fxy) * DX;
                const float cx = wgt * (pa.z + pb.x * dpx + pb.y * dpy);
                const float cy = wgt * (pa.w + pb.z * dpx + pb.w * dpy);
                float* base = &acc[((li + i) * REG + (lj + j)) * 3];
                lds_fadd(base + 0, cx);
                lds_fadd(base + 1, cy);
                lds_fadd(base + 2, wgt * P_MASS);
            }
        }
    }
    // CRITICAL: drain this wave's in-flight ds_add_f32 before the barrier —
    // the compiler cannot see inline-asm DS ops and will not emit the wait.
    lds_drain();
    __syncthreads();

    // writeout: plain stores for exclusive interior, device-scope atomics for
    // the halo ring (written by up to 4 blocks on different XCDs).
    for (int idx = threadIdx.x; idx < RCELL; idx += PBLK) {
        const int lr = idx / REG, lc = idx % REG;
        const int gr = r0 + lr, gc = c0 + lc;
        if ((unsigned)gr >= (unsigned)NGRID || (unsigned)gc >= (unsigned)NGRID) continue;
        const int g = gr * NGRID + gc;
        const float vx = acc[idx * 3 + 0];
        const float vy = acc[idx * 3 + 1];
        const float m  = acc[idx * 3 + 2];
        const bool interior = (lr >= 3 && lr <= 15 && lc >= 3 && lc <= 15);
        if (interior) {
            gvx[g] = vx; gvy[g] = vy; gm[g] = m;
        } else {
            if (vx != 0.0f) atomicAdd(&gvx[g], vx);
            if (vy != 0.0f) atomicAdd(&gvy[g], vy);
            if (m  != 0.0f) atomicAdd(&gm[g],  m);
        }
    }
}

// ----------------------------------------------------------- grid update ----
__global__ __launch_bounds__(256) void k_grid(
    const float* __restrict__ gvx, const float* __restrict__ gvy,
    const float* __restrict__ gm, float2* __restrict__ gv)
{
    const int idx = blockIdx.x * blockDim.x + threadIdx.x;
    if (idx >= NCELL) return;
    const int i = idx >> 9;
    const int j = idx & (NGRID - 1);
    float m = gm[idx], vx = gvx[idx], vy = gvy[idx];
    if (m > 0.0f) {
        const float inv = 1.0f / fmaxf(m, 1e-30f);
        vx *= inv; vy *= inv;
    }
    vy -= DT * GRAV;
    if (i < 3)          vx = fmaxf(vx, 0.0f);
    if (i >= NGRID - 2) vx = fminf(vx, 0.0f);
    if (j < 3)          vy = fmaxf(vy, 0.0f);
    if (j >= NGRID - 2) vy = fminf(vy, 0.0f);
    gv[idx] = make_float2(vx, vy);
}

// ------------------------------------------------------------------ g2p ----
__global__ __launch_bounds__(256) void k_g2p(
    const float2* __restrict__ x,
    const float2* __restrict__ gv,
    float2* __restrict__ outX,
    float2* __restrict__ outV,
    float4* __restrict__ outC,
    int n)
{
    const int p = blockIdx.x * blockDim.x + threadIdx.x;
    if (p >= n) return;

    const float2 xp = x[p];
    const float xs = xp.x * INV_DX, ys = xp.y * INV_DX;
    const int bi = (int)(xs - 0.5f);
    const int bj = (int)(ys - 0.5f);
    const float fxx = xs - (float)bi;
    const float fxy = ys - (float)bj;

    float wx[3], wy[3];
    { float t0 = 1.5f - fxx, t1 = fxx - 1.0f, t2 = fxx - 0.5f;
      wx[0] = 0.5f * t0 * t0; wx[1] = 0.75f - t1 * t1; wx[2] = 0.5f * t2 * t2; }
    { float t0 = 1.5f - fxy, t1 = fxy - 1.0f, t2 = fxy - 0.5f;
      wy[0] = 0.5f * t0 * t0; wy[1] = 0.75f - t1 * t1; wy[2] = 0.5f * t2 * t2; }

    float nvx = 0.0f, nvy = 0.0f;
    float C00 = 0.0f, C01 = 0.0f, C10 = 0.0f, C11 = 0.0f;
    constexpr float K4 = 4.0f * INV_DX * INV_DX;

    #pragma unroll
    for (int i = 0; i < 3; ++i) {
        const float dpx = ((float)i - fxx) * DX;
        const int rowbase = (bi + i) * NGRID + bj;
        #pragma unroll
        for (int j = 0; j < 3; ++j) {
            const float wgt = wx[i] * wy[j];
            const float dpy = ((float)j - fxy) * DX;
            const float2 g = gv[rowbase + j];
            nvx += wgt * g.x;
            nvy += wgt * g.y;
            const float kw = K4 * wgt;
            C00 += kw * g.x * dpx;
            C01 += kw * g.x * dpy;
            C10 += kw * g.y * dpx;
            C11 += kw * g.y * dpy;
        }
    }

    outX[p] = make_float2(xp.x + DT * nvx, xp.y + DT * nvy);
    outV[p] = make_float2(nvx, nvy);
    outC[p] = make_float4(C00, C01, C10, C11);
}

// ------------------------------------------- fallback (small ws): atomics ----
__global__ __launch_bounds__(256) void fb_p2g(
    const float2* __restrict__ x, const float2* __restrict__ v,
    const float4* __restrict__ C, const float4* __restrict__ F,
    const int* __restrict__ material, const float* __restrict__ Jp,
    const float* __restrict__ Ep, const float* __restrict__ nup,
    float* __restrict__ g,           // NCELL x 3 interleaved
    float4* __restrict__ outF, float* __restrict__ outMat, float* __restrict__ outJp,
    int n)
{
    const int p = blockIdx.x * blockDim.x + threadIdx.x;
    if (p >= n) return;
    const float E = Ep[0], nu = nup[0];
    const float mu0 = E / (2.0f * (1.0f + nu));
    const float la0 = E * nu / ((1.0f + nu) * (1.0f - 2.0f * nu));
    const float2 xp = x[p]; const float2 vp = v[p];
    const float4 c4 = C[p]; const float4 f4 = F[p];
    const float jp = Jp[p];
    const float xs = xp.x * INV_DX, ys = xp.y * INV_DX;
    const int bi = (int)(xs - 0.5f), bj = (int)(ys - 0.5f);
    const float fxx = xs - (float)bi, fxy = ys - (float)bj;
    float wx[3], wy[3];
    { float t0 = 1.5f - fxx, t1 = fxx - 1.0f, t2 = fxx - 0.5f;
      wx[0] = 0.5f * t0 * t0; wx[1] = 0.75f - t1 * t1; wx[2] = 0.5f * t2 * t2; }
    { float t0 = 1.5f - fxy, t1 = fxy - 1.0f, t2 = fxy - 0.5f;
      wy[0] = 0.5f * t0 * t0; wy[1] = 0.75f - t1 * t1; wy[2] = 0.5f * t2 * t2; }
    const float F00 = f4.x + DT * (c4.x * f4.x + c4.y * f4.z);
    const float F01 = f4.y + DT * (c4.x * f4.y + c4.y * f4.w);
    const float F10 = f4.z + DT * (c4.z * f4.x + c4.w * f4.z);
    const float F11 = f4.w + DT * (c4.z * f4.y + c4.w * f4.w);
    const float h = expf(10.0f * (1.0f - jp));
    const float mu = mu0 * h, la = la0 * h;
    const float a = F00 + F11, b = F10 - F01;
    const float r = sqrtf(a * a + b * b);
    const float cth = a / r, sth = b / r;
    const float J = fabsf(F00 * F11 - F01 * F10);
    const float A00 = F00 - cth, A01 = F01 + sth;
    const float A10 = F10 - sth, A11 = F11 - cth;
    constexpr float SC = -DT * P_VOL * 4.0f * INV_DX * INV_DX;
    const float diag = la * J * (J - 1.0f);
    const float twomu = 2.0f * mu;
    const float Af00 = SC * (twomu * (A00 * F00 + A01 * F01) + diag) + P_MASS * c4.x;
    const float Af01 = SC * (twomu * (A00 * F10 + A01 * F11))        + P_MASS * c4.y;
    const float Af10 = SC * (twomu * (A10 * F00 + A11 * F01))        + P_MASS * c4.z;
    const float Af11 = SC * (twomu * (A10 * F10 + A11 * F11) + diag) + P_MASS * c4.w;
    const float mvx = P_MASS * vp.x, mvy = P_MASS * vp.y;
    #pragma unroll
    for (int i = 0; i < 3; ++i) {
        #pragma unroll
        for (int j = 0; j < 3; ++j) {
            const float wgt = wx[i] * wy[j];
            const float dpx = ((float)i - fxx) * DX;
            const float dpy = ((float)j - fxy) * DX;
            const size_t k3 = (size_t)((bi + i) * NGRID + (bj + j)) * 3;
            atomicAdd(&g[k3 + 0], wgt * (mvx + Af00 * dpx + Af01 * dpy));
            atomicAdd(&g[k3 + 1], wgt * (mvy + Af10 * dpx + Af11 * dpy));
            atomicAdd(&g[k3 + 2], wgt * P_MASS);
        }
    }
    outF[p] = make_float4(F00, F01, F10, F11);
    outMat[p] = (float)material[p];
    outJp[p] = jp;
}

__global__ __launch_bounds__(256) void fb_grid(
    const float* __restrict__ g, float2* __restrict__ gv)
{
    const int idx = blockIdx.x * blockDim.x + threadIdx.x;
    if (idx >= NCELL) return;
    const int i = idx >> 9, j = idx & (NGRID - 1);
    float vx = g[(size_t)idx * 3], vy = g[(size_t)idx * 3 + 1], m = g[(size_t)idx * 3 + 2];
    if (m > 0.0f) { const float inv = 1.0f / fmaxf(m, 1e-30f); vx *= inv; vy *= inv; }
    vy -= DT * GRAV;
    if (i < 3)          vx = fmaxf(vx, 0.0f);
    if (i >= NGRID - 2) vx = fminf(vx, 0.0f);
    if (j < 3)          vy = fmaxf(vy, 0.0f);
    if (j >= NGRID - 2) vy = fminf(vy, 0.0f);
    gv[idx] = make_float2(vx, vy);
}

extern "C" void kernel_launch(void* const* d_in, const int* in_sizes, int n_in,
                              void* d_out, int out_size, void* d_ws, size_t ws_size,
                              hipStream_t stream) {
    const int n = in_sizes[0] / 2;   // N_PART

    const float2* x   = (const float2*)d_in[0];
    const float2* v   = (const float2*)d_in[1];
    const float4* C   = (const float4*)d_in[2];
    const float4* F   = (const float4*)d_in[3];
    const int*    mat = (const int*)d_in[4];
    const float*  Jp  = (const float*)d_in[5];
    const float*  Ep  = (const float*)d_in[6];
    const float*  nup = (const float*)d_in[7];

    float* out = (float*)d_out;
    float2* o_x = (float2*)(out);
    float2* o_v = (float2*)(out + 2 * (size_t)n);
    float4* o_C = (float4*)(out + 4 * (size_t)n);
    float4* o_F = (float4*)(out + 8 * (size_t)n);
    float*  o_m = out + 12 * (size_t)n;
    float*  o_J = out + 13 * (size_t)n;

    const int BLOCK = 256;
    const int pgrid = (n + BLOCK - 1) / BLOCK;
    const int ggrid = (NCELL + BLOCK - 1) / BLOCK;

    // fast-path workspace layout
    char* w = (char*)d_ws;
    float4* packed = (float4*)w;            w += (size_t)n * 2 * sizeof(float4);
    int* cnt    = (int*)w;                  w += (size_t)NBLK * NTILE * sizeof(int);
    int* tstart = (int*)w;                  w += (size_t)NTILE * sizeof(int);
    int* tend   = (int*)w;                  w += (size_t)NTILE * sizeof(int);
    float* gvx  = (float*)w;                w += (size_t)NCELL * sizeof(float);
    float* gvy  = (float*)w;                w += (size_t)NCELL * sizeof(float);
    float* gm   = (float*)w;                w += (size_t)NCELL * sizeof(float);
    float2* gfin= (float2*)w;               w += (size_t)NCELL * sizeof(float2);
    const size_t need = (size_t)(w - (char*)d_ws);

    if (ws_size >= need) {
        const int ppb = (n + NBLK - 1) / NBLK;
        hipMemsetAsync(gvx, 0, (size_t)NCELL * 3 * sizeof(float), stream);
        k_count  <<<NBLK, BLOCK, 0, stream>>>(x, n, ppb, cnt);
        k_scan   <<<1, 1024, 0, stream>>>(cnt, tstart, tend);
        k_scatter<<<NBLK, BLOCK, 0, stream>>>(x, v, C, F, mat, Jp, Ep, nup,
                                              n, ppb, cnt, packed, o_F, o_m, o_J);
        k_p2g_tile<<<NTILE, PBLK, 0, stream>>>(packed, tstart, tend, gvx, gvy, gm);
        k_grid   <<<ggrid, BLOCK, 0, stream>>>(gvx, gvy, gm, gfin);
        k_g2p    <<<pgrid, BLOCK, 0, stream>>>(x, gfin, o_x, o_v, o_C, n);
    } else {
        // fallback: single grid copy + device atomics
        float* g = (float*)d_ws;                       // NCELL*3
        float2* gf = (float2*)(g + (size_t)NCELL * 3); // NCELL float2
        hipMemsetAsync(g, 0, (size_t)NCELL * 3 * sizeof(float), stream);
        fb_p2g <<<pgrid, BLOCK, 0, stream>>>(x, v, C, F, mat, Jp, Ep, nup,
                                             g, o_F, o_m, o_J, n);
        fb_grid<<<ggrid, BLOCK, 0, stream>>>(g, gf);
        k_g2p  <<<pgrid, BLOCK, 0, stream>>>(x, gf, o_x, o_v, o_C, n);
    }
}

// Round 9
// 497.222 us; speedup vs baseline: 1.5592x; 1.5592x over previous
//
#include <hip/hip_runtime.h>

namespace {
constexpr int   NGRID  = 512;
constexpr int   NCELL  = NGRID * NGRID;
constexpr float DX     = 1.0f / (float)NGRID;
constexpr float INV_DX = (float)NGRID;
constexpr float DT     = 1e-4f;
constexpr float P_VOL  = (DX * 0.5f) * (DX * 0.5f);
constexpr float P_MASS = P_VOL * 1.0f;   // p_rho = 1
constexpr float GRAV   = 10.0f;

constexpr int TILE  = 16;            // cells per tile side
constexpr int TPR   = NGRID / TILE;  // 32 tiles per row
constexpr int NTILE = TPR * TPR;     // 1024
constexpr int REG   = TILE + 3;      // 19 region rows: r0 .. r0+18 (r0 = tile*16-1)
constexpr int RCELL = REG * REG;     // 361
constexpr int NBLK  = 512;           // blocks for count/scatter
constexpr int BLK   = 256;
constexpr int PBLK  = 512;           // threads for p2g_tile
constexpr int CAP   = 3456;          // max particles staged per tile (lambda~3052, sigma~55)
constexpr int BINS  = 17 * 17;       // base-cell bins per tile (bi-r0 in 0..16)
}

// Lessons ledger:
//  - r1/r2: global fp atomicAdd = far-atomic CAS at ~20 G/s chip-wide; scope
//    annotations don't help. Avoid bulk global fp atomics.
//  - r3/r6: LDS fp atomics (CAS *or* native ds_add_f32) both saturate the
//    per-CU LDS atomic RMW path at ~4.6 cyc/lane-op => 54M scattered LDS fp
//    RMWs cost ~405 us regardless of instruction choice. Avoid bulk LDS fp
//    atomics too; accumulate in REGISTERS (gather form).
//  - r4: hand-rolled global_atomic_add_f32 w/o scope flags races across XCDs.
//  - r5: inline-asm DS ops need explicit s_waitcnt lgkmcnt(0) before barriers.
//  This version uses NO inline asm and NO fp atomics in the hot path.

// quadratic B-spline weight component d (0..2) for fractional position fx
__device__ __forceinline__ float quadw(int d, float fx) {
    const float t0 = 1.5f - fx, t1 = fx - 1.0f, t2 = fx - 0.5f;
    const float w0 = 0.5f * t0 * t0;
    const float w1 = 0.75f - t1 * t1;
    const float w2 = 0.5f * t2 * t2;
    return d == 0 ? w0 : (d == 1 ? w1 : w2);
}

// ---------------------------------------------------------------- count ----
__global__ __launch_bounds__(256) void k_count(
    const float2* __restrict__ x, int n, int ppb,
    int* __restrict__ cnt /* [NBLK][NTILE] */)
{
    __shared__ int hist[NTILE];
    for (int t = threadIdx.x; t < NTILE; t += BLK) hist[t] = 0;
    __syncthreads();
    const int b0 = blockIdx.x * ppb;
    const int b1 = min(b0 + ppb, n);
    for (int p = b0 + threadIdx.x; p < b1; p += BLK) {
        const float2 xp = x[p];
        const int ci = (int)(xp.x * INV_DX);
        const int cj = (int)(xp.y * INV_DX);
        atomicAdd(&hist[(ci >> 4) * TPR + (cj >> 4)], 1);   // int: native
    }
    __syncthreads();
    int* row = cnt + (size_t)blockIdx.x * NTILE;
    for (int t = threadIdx.x; t < NTILE; t += BLK) row[t] = hist[t];
}

// ----------------------------------------------------------------- scan ----
__global__ __launch_bounds__(1024) void k_scan(
    int* __restrict__ cnt, int* __restrict__ tile_start, int* __restrict__ tile_end)
{
    const int t = threadIdx.x;
    int s = 0;
    #pragma unroll 8
    for (int b = 0; b < NBLK; ++b) s += cnt[(size_t)b * NTILE + t];

    __shared__ int wsum[16];
    const int lane = t & 63, w = t >> 6;
    int inc = s;
    #pragma unroll
    for (int d = 1; d < 64; d <<= 1) {
        int u = __shfl_up(inc, d, 64);
        if (lane >= d) inc += u;
    }
    if (lane == 63) wsum[w] = inc;
    __syncthreads();
    if (t == 0) {
        int r = 0;
        #pragma unroll
        for (int i = 0; i < 16; ++i) { int v = wsum[i]; wsum[i] = r; r += v; }
    }
    __syncthreads();
    const int base = wsum[w] + inc - s;
    tile_start[t] = base;
    tile_end[t]   = base + s;

    int run = base;
    #pragma unroll 8
    for (int b = 0; b < NBLK; ++b) {
        int v = cnt[(size_t)b * NTILE + t];
        cnt[(size_t)b * NTILE + t] = run;
        run += v;
    }
}

// -------------------------------------------------------------- scatter ----
__global__ __launch_bounds__(256) void k_scatter(
    const float2* __restrict__ x,
    const float2* __restrict__ v,
    const float4* __restrict__ C,
    const float4* __restrict__ F,
    const int*    __restrict__ material,
    const float*  __restrict__ Jp,
    const float*  __restrict__ Ep,
    const float*  __restrict__ nup,
    int n, int ppb,
    const int* __restrict__ cnt,
    float4* __restrict__ packed,
    float4* __restrict__ outF,
    float*  __restrict__ outMat,
    float*  __restrict__ outJp)
{
    __shared__ int cur[NTILE];
    {
        const int* row = cnt + (size_t)blockIdx.x * NTILE;
        for (int t = threadIdx.x; t < NTILE; t += BLK) cur[t] = row[t];
    }
    __syncthreads();

    const float E  = Ep[0];
    const float nu = nup[0];
    const float mu0 = E / (2.0f * (1.0f + nu));
    const float la0 = E * nu / ((1.0f + nu) * (1.0f - 2.0f * nu));

    const int b0 = blockIdx.x * ppb;
    const int b1 = min(b0 + ppb, n);
    for (int p = b0 + threadIdx.x; p < b1; p += BLK) {
        const float2 xp = x[p];
        const float2 vp = v[p];
        const float4 c4 = C[p];
        const float4 f4 = F[p];
        const float  jp = Jp[p];

        const float F00 = f4.x + DT * (c4.x * f4.x + c4.y * f4.z);
        const float F01 = f4.y + DT * (c4.x * f4.y + c4.y * f4.w);
        const float F10 = f4.z + DT * (c4.z * f4.x + c4.w * f4.z);
        const float F11 = f4.w + DT * (c4.z * f4.y + c4.w * f4.w);

        const float h  = expf(10.0f * (1.0f - jp));
        const float mu = mu0 * h;
        const float la = la0 * h;

        const float a = F00 + F11;
        const float b = F10 - F01;
        const float r = sqrtf(a * a + b * b);
        const float cth = a / r;
        const float sth = b / r;
        const float J = fabsf(F00 * F11 - F01 * F10);

        const float A00 = F00 - cth, A01 = F01 + sth;
        const float A10 = F10 - sth, A11 = F11 - cth;
        const float PF00 = A00 * F00 + A01 * F01;
        const float PF01 = A00 * F10 + A01 * F11;
        const float PF10 = A10 * F00 + A11 * F01;
        const float PF11 = A10 * F10 + A11 * F11;

        constexpr float SC = -DT * P_VOL * 4.0f * INV_DX * INV_DX;
        const float diag = la * J * (J - 1.0f);
        const float twomu = 2.0f * mu;
        const float Af00 = SC * (twomu * PF00 + diag) + P_MASS * c4.x;
        const float Af01 = SC * (twomu * PF01)        + P_MASS * c4.y;
        const float Af10 = SC * (twomu * PF10)        + P_MASS * c4.z;
        const float Af11 = SC * (twomu * PF11 + diag) + P_MASS * c4.w;

        const int ci = (int)(xp.x * INV_DX);
        const int cj = (int)(xp.y * INV_DX);
        const int t  = (ci >> 4) * TPR + (cj >> 4);
        const int slot = atomicAdd(&cur[t], 1);      // int LDS atomic: native

        packed[2 * (size_t)slot]     = make_float4(xp.x, xp.y, P_MASS * vp.x, P_MASS * vp.y);
        packed[2 * (size_t)slot + 1] = make_float4(Af00, Af01, Af10, Af11);

        outF[p]   = make_float4(F00, F01, F10, F11);
        outMat[p] = (float)material[p];
        outJp[p]  = jp;
    }
}

// --------------------------------------- p2g tile: sort-by-cell + GATHER ----
__global__ __launch_bounds__(PBLK) void k_p2g_tile(
    const float4* __restrict__ packed,
    const int* __restrict__ tile_start,
    const int* __restrict__ tile_end,
    float* __restrict__ gvx, float* __restrict__ gvy, float* __restrict__ gm)
{
    const int t  = blockIdx.x;
    const int s0 = tile_start[t];
    const int s1 = tile_end[t];
    if (s0 == s1) return;                       // uniform: safe before barriers

    __shared__ float4 rec[2 * CAP];             // 110.6 KB staged records
    __shared__ unsigned short perm[CAP];        // cell-sorted particle order
    __shared__ unsigned short binof[CAP];       // per-particle bin
    __shared__ int bcnt[BINS];                  // counts -> cursors -> ends
    __shared__ int boffs[BINS];                 // bucket starts
    __shared__ int wscan[8];

    const int tid = threadIdx.x;
    const int tr = t >> 5, tc = t & 31;         // TPR = 32
    const int r0 = tr * TILE - 1, c0 = tc * TILE - 1;

    const int nseg = s1 - s0;
    const int nin  = min(nseg, CAP);
    const bool ovf = (nseg > CAP);              // statistically ~never

    for (int b = tid; b < BINS; b += PBLK) bcnt[b] = 0;
    __syncthreads();

    // phase 1: stage records in LDS + histogram base cells (int LDS atomics)
    for (int k = tid; k < nin; k += PBLK) {
        const float4 pa = packed[2 * (size_t)(s0 + k)];
        const float4 pb = packed[2 * (size_t)(s0 + k) + 1];
        rec[2 * k]     = pa;
        rec[2 * k + 1] = pb;
        const int bi = (int)(pa.x * INV_DX - 0.5f);
        const int bj = (int)(pa.y * INV_DX - 0.5f);
        const int bin = (bi - r0) * 17 + (bj - c0);
        binof[k] = (unsigned short)bin;
        atomicAdd(&bcnt[bin], 1);
    }
    __syncthreads();

    // phase 2: parallel exclusive scan of 289 bins (5 waves of 64)
    int vv = 0, incl = 0;
    if (tid < 320) {
        vv = (tid < BINS) ? bcnt[tid] : 0;
        incl = vv;
        const int lane = tid & 63;
        #pragma unroll
        for (int d = 1; d < 64; d <<= 1) {
            int u = __shfl_up(incl, d, 64);
            if (lane >= d) incl += u;
        }
        if (lane == 63) wscan[tid >> 6] = incl;
    }
    __syncthreads();
    if (tid == 0) {
        int run = 0;
        #pragma unroll
        for (int i = 0; i < 5; ++i) { int w = wscan[i]; wscan[i] = run; run += w; }
    }
    __syncthreads();
    if (tid < BINS) {
        const int excl = incl - vv + wscan[tid >> 6];
        boffs[tid] = excl;
        bcnt[tid]  = excl;                      // becomes cursor
    }
    __syncthreads();

    // phase 3: fill cell-sorted permutation
    for (int k = tid; k < nin; k += PBLK) {
        const int bin = binof[k];
        const int rk = atomicAdd(&bcnt[bin], 1);
        perm[rk] = (unsigned short)k;
    }
    __syncthreads();

    // overflow slow path (correctness only; never triggers for this input)
    if (ovf) {
        for (int k = CAP + tid; k < nseg; k += PBLK) {
            const float4 pa = packed[2 * (size_t)(s0 + k)];
            const float4 pb = packed[2 * (size_t)(s0 + k) + 1];
            const float xs = pa.x * INV_DX, ys = pa.y * INV_DX;
            const int bi = (int)(xs - 0.5f), bj = (int)(ys - 0.5f);
            const float fxx = xs - (float)bi, fxy = ys - (float)bj;
            for (int i = 0; i < 3; ++i)
                for (int j = 0; j < 3; ++j) {
                    const float wgt = quadw(i, fxx) * quadw(j, fxy);
                    const float dpx = ((float)i - fxx) * DX;
                    const float dpy = ((float)j - fxy) * DX;
                    const int g = (bi + i) * NGRID + (bj + j);
                    atomicAdd(&gvx[g], wgt * (pa.z + pb.x * dpx + pb.y * dpy));
                    atomicAdd(&gvy[g], wgt * (pa.w + pb.z * dpx + pb.w * dpy));
                    atomicAdd(&gm[g],  wgt * P_MASS);
                }
        }
    }

    // phase 4: per-cell register gather over 9 inverse-stencil buckets
    for (int idx = tid; idx < RCELL; idx += PBLK) {
        const int lr = idx / REG, lc = idx % REG;
        float vx = 0.0f, vy = 0.0f, m = 0.0f;

        #pragma unroll
        for (int di = 0; di < 3; ++di) {
            const int bli = lr - di;
            if ((unsigned)bli > 16u) continue;
            #pragma unroll
            for (int dj = 0; dj < 3; ++dj) {
                const int blj = lc - dj;
                if ((unsigned)blj > 16u) continue;
                const int b = bli * 17 + blj;
                const int k0 = boffs[b], k1 = bcnt[b];
                for (int k = k0; k < k1; ++k) {
                    const int pp = perm[k];
                    const float4 pa = rec[2 * pp];
                    const float4 pb = rec[2 * pp + 1];
                    const float xs = pa.x * INV_DX, ys = pa.y * INV_DX;
                    const float fxx = xs - (float)((int)(xs - 0.5f));
                    const float fxy = ys - (float)((int)(ys - 0.5f));
                    const float wgt = quadw(di, fxx) * quadw(dj, fxy);
                    const float dpx = ((float)di - fxx) * DX;
                    const float dpy = ((float)dj - fxy) * DX;
                    vx += wgt * (pa.z + pb.x * dpx + pb.y * dpy);
                    vy += wgt * (pa.w + pb.z * dpx + pb.w * dpy);
                    m  += wgt * P_MASS;
                }
            }
        }

        const int gr = r0 + lr, gc = c0 + lc;
        if ((unsigned)gr >= (unsigned)NGRID || (unsigned)gc >= (unsigned)NGRID) continue;
        const int g = gr * NGRID + gc;
        const bool interior = (lr >= 3 && lr <= 15 && lc >= 3 && lc <= 15) && !ovf;
        if (interior) {
            gvx[g] = vx; gvy[g] = vy; gm[g] = m;
        } else {
            if (vx != 0.0f) atomicAdd(&gvx[g], vx);
            if (vy != 0.0f) atomicAdd(&gvy[g], vy);
            if (m  != 0.0f) atomicAdd(&gm[g],  m);
        }
    }
}

// ----------------------------------------------------------- grid update ----
__global__ __launch_bounds__(256) void k_grid(
    const float* __restrict__ gvx, const float* __restrict__ gvy,
    const float* __restrict__ gm, float2* __restrict__ gv)
{
    const int idx = blockIdx.x * blockDim.x + threadIdx.x;
    if (idx >= NCELL) return;
    const int i = idx >> 9;
    const int j = idx & (NGRID - 1);
    float m = gm[idx], vx = gvx[idx], vy = gvy[idx];
    if (m > 0.0f) {
        const float inv = 1.0f / fmaxf(m, 1e-30f);
        vx *= inv; vy *= inv;
    }
    vy -= DT * GRAV;
    if (i < 3)          vx = fmaxf(vx, 0.0f);
    if (i >= NGRID - 2) vx = fminf(vx, 0.0f);
    if (j < 3)          vy = fmaxf(vy, 0.0f);
    if (j >= NGRID - 2) vy = fminf(vy, 0.0f);
    gv[idx] = make_float2(vx, vy);
}

// ------------------------------------------------------------------ g2p ----
__global__ __launch_bounds__(256) void k_g2p(
    const float2* __restrict__ x,
    const float2* __restrict__ gv,
    float2* __restrict__ outX,
    float2* __restrict__ outV,
    float4* __restrict__ outC,
    int n)
{
    const int p = blockIdx.x * blockDim.x + threadIdx.x;
    if (p >= n) return;

    const float2 xp = x[p];
    const float xs = xp.x * INV_DX, ys = xp.y * INV_DX;
    const int bi = (int)(xs - 0.5f);
    const int bj = (int)(ys - 0.5f);
    const float fxx = xs - (float)bi;
    const float fxy = ys - (float)bj;

    float wx[3], wy[3];
    { float t0 = 1.5f - fxx, t1 = fxx - 1.0f, t2 = fxx - 0.5f;
      wx[0] = 0.5f * t0 * t0; wx[1] = 0.75f - t1 * t1; wx[2] = 0.5f * t2 * t2; }
    { float t0 = 1.5f - fxy, t1 = fxy - 1.0f, t2 = fxy - 0.5f;
      wy[0] = 0.5f * t0 * t0; wy[1] = 0.75f - t1 * t1; wy[2] = 0.5f * t2 * t2; }

    float nvx = 0.0f, nvy = 0.0f;
    float C00 = 0.0f, C01 = 0.0f, C10 = 0.0f, C11 = 0.0f;
    constexpr float K4 = 4.0f * INV_DX * INV_DX;

    #pragma unroll
    for (int i = 0; i < 3; ++i) {
        const float dpx = ((float)i - fxx) * DX;
        const int rowbase = (bi + i) * NGRID + bj;
        #pragma unroll
        for (int j = 0; j < 3; ++j) {
            const float wgt = wx[i] * wy[j];
            const float dpy = ((float)j - fxy) * DX;
            const float2 g = gv[rowbase + j];
            nvx += wgt * g.x;
            nvy += wgt * g.y;
            const float kw = K4 * wgt;
            C00 += kw * g.x * dpx;
            C01 += kw * g.x * dpy;
            C10 += kw * g.y * dpx;
            C11 += kw * g.y * dpy;
        }
    }

    outX[p] = make_float2(xp.x + DT * nvx, xp.y + DT * nvy);
    outV[p] = make_float2(nvx, nvy);
    outC[p] = make_float4(C00, C01, C10, C11);
}

// ------------------------------------------- fallback (small ws): atomics ----
__global__ __launch_bounds__(256) void fb_p2g(
    const float2* __restrict__ x, const float2* __restrict__ v,
    const float4* __restrict__ C, const float4* __restrict__ F,
    const int* __restrict__ material, const float* __restrict__ Jp,
    const float* __restrict__ Ep, const float* __restrict__ nup,
    float* __restrict__ g,           // NCELL x 3 interleaved
    float4* __restrict__ outF, float* __restrict__ outMat, float* __restrict__ outJp,
    int n)
{
    const int p = blockIdx.x * blockDim.x + threadIdx.x;
    if (p >= n) return;
    const float E = Ep[0], nu = nup[0];
    const float mu0 = E / (2.0f * (1.0f + nu));
    const float la0 = E * nu / ((1.0f + nu) * (1.0f - 2.0f * nu));
    const float2 xp = x[p]; const float2 vp = v[p];
    const float4 c4 = C[p]; const float4 f4 = F[p];
    const float jp = Jp[p];
    const float xs = xp.x * INV_DX, ys = xp.y * INV_DX;
    const int bi = (int)(xs - 0.5f), bj = (int)(ys - 0.5f);
    const float fxx = xs - (float)bi, fxy = ys - (float)bj;
    float wx[3], wy[3];
    { float t0 = 1.5f - fxx, t1 = fxx - 1.0f, t2 = fxx - 0.5f;
      wx[0] = 0.5f * t0 * t0; wx[1] = 0.75f - t1 * t1; wx[2] = 0.5f * t2 * t2; }
    { float t0 = 1.5f - fxy, t1 = fxy - 1.0f, t2 = fxy - 0.5f;
      wy[0] = 0.5f * t0 * t0; wy[1] = 0.75f - t1 * t1; wy[2] = 0.5f * t2 * t2; }
    const float F00 = f4.x + DT * (c4.x * f4.x + c4.y * f4.z);
    const float F01 = f4.y + DT * (c4.x * f4.y + c4.y * f4.w);
    const float F10 = f4.z + DT * (c4.z * f4.x + c4.w * f4.z);
    const float F11 = f4.w + DT * (c4.z * f4.y + c4.w * f4.w);
    const float h = expf(10.0f * (1.0f - jp));
    const float mu = mu0 * h, la = la0 * h;
    const float a = F00 + F11, b = F10 - F01;
    const float r = sqrtf(a * a + b * b);
    const float cth = a / r, sth = b / r;
    const float J = fabsf(F00 * F11 - F01 * F10);
    const float A00 = F00 - cth, A01 = F01 + sth;
    const float A10 = F10 - sth, A11 = F11 - cth;
    constexpr float SC = -DT * P_VOL * 4.0f * INV_DX * INV_DX;
    const float diag = la * J * (J - 1.0f);
    const float twomu = 2.0f * mu;
    const float Af00 = SC * (twomu * (A00 * F00 + A01 * F01) + diag) + P_MASS * c4.x;
    const float Af01 = SC * (twomu * (A00 * F10 + A01 * F11))        + P_MASS * c4.y;
    const float Af10 = SC * (twomu * (A10 * F00 + A11 * F01))        + P_MASS * c4.z;
    const float Af11 = SC * (twomu * (A10 * F10 + A11 * F11) + diag) + P_MASS * c4.w;
    const float mvx = P_MASS * vp.x, mvy = P_MASS * vp.y;
    #pragma unroll
    for (int i = 0; i < 3; ++i) {
        #pragma unroll
        for (int j = 0; j < 3; ++j) {
            const float wgt = wx[i] * wy[j];
            const float dpx = ((float)i - fxx) * DX;
            const float dpy = ((float)j - fxy) * DX;
            const size_t k3 = (size_t)((bi + i) * NGRID + (bj + j)) * 3;
            atomicAdd(&g[k3 + 0], wgt * (mvx + Af00 * dpx + Af01 * dpy));
            atomicAdd(&g[k3 + 1], wgt * (mvy + Af10 * dpx + Af11 * dpy));
            atomicAdd(&g[k3 + 2], wgt * P_MASS);
        }
    }
    outF[p] = make_float4(F00, F01, F10, F11);
    outMat[p] = (float)material[p];
    outJp[p] = jp;
}

__global__ __launch_bounds__(256) void fb_grid(
    const float* __restrict__ g, float2* __restrict__ gv)
{
    const int idx = blockIdx.x * blockDim.x + threadIdx.x;
    if (idx >= NCELL) return;
    const int i = idx >> 9, j = idx & (NGRID - 1);
    float vx = g[(size_t)idx * 3], vy = g[(size_t)idx * 3 + 1], m = g[(size_t)idx * 3 + 2];
    if (m > 0.0f) { const float inv = 1.0f / fmaxf(m, 1e-30f); vx *= inv; vy *= inv; }
    vy -= DT * GRAV;
    if (i < 3)          vx = fmaxf(vx, 0.0f);
    if (i >= NGRID - 2) vx = fminf(vx, 0.0f);
    if (j < 3)          vy = fmaxf(vy, 0.0f);
    if (j >= NGRID - 2) vy = fminf(vy, 0.0f);
    gv[idx] = make_float2(vx, vy);
}

extern "C" void kernel_launch(void* const* d_in, const int* in_sizes, int n_in,
                              void* d_out, int out_size, void* d_ws, size_t ws_size,
                              hipStream_t stream) {
    const int n = in_sizes[0] / 2;   // N_PART

    const float2* x   = (const float2*)d_in[0];
    const float2* v   = (const float2*)d_in[1];
    const float4* C   = (const float4*)d_in[2];
    const float4* F   = (const float4*)d_in[3];
    const int*    mat = (const int*)d_in[4];
    const float*  Jp  = (const float*)d_in[5];
    const float*  Ep  = (const float*)d_in[6];
    const float*  nup = (const float*)d_in[7];

    float* out = (float*)d_out;
    float2* o_x = (float2*)(out);
    float2* o_v = (float2*)(out + 2 * (size_t)n);
    float4* o_C = (float4*)(out + 4 * (size_t)n);
    float4* o_F = (float4*)(out + 8 * (size_t)n);
    float*  o_m = out + 12 * (size_t)n;
    float*  o_J = out + 13 * (size_t)n;

    const int BLOCK = 256;
    const int pgrid = (n + BLOCK - 1) / BLOCK;
    const int ggrid = (NCELL + BLOCK - 1) / BLOCK;

    // fast-path workspace layout
    char* w = (char*)d_ws;
    float4* packed = (float4*)w;            w += (size_t)n * 2 * sizeof(float4);
    int* cnt    = (int*)w;                  w += (size_t)NBLK * NTILE * sizeof(int);
    int* tstart = (int*)w;                  w += (size_t)NTILE * sizeof(int);
    int* tend   = (int*)w;                  w += (size_t)NTILE * sizeof(int);
    float* gvx  = (float*)w;                w += (size_t)NCELL * sizeof(float);
    float* gvy  = (float*)w;                w += (size_t)NCELL * sizeof(float);
    float* gm   = (float*)w;                w += (size_t)NCELL * sizeof(float);
    float2* gfin= (float2*)w;               w += (size_t)NCELL * sizeof(float2);
    const size_t need = (size_t)(w - (char*)d_ws);

    if (ws_size >= need) {
        const int ppb = (n + NBLK - 1) / NBLK;
        hipMemsetAsync(gvx, 0, (size_t)NCELL * 3 * sizeof(float), stream);
        k_count  <<<NBLK, BLOCK, 0, stream>>>(x, n, ppb, cnt);
        k_scan   <<<1, 1024, 0, stream>>>(cnt, tstart, tend);
        k_scatter<<<NBLK, BLOCK, 0, stream>>>(x, v, C, F, mat, Jp, Ep, nup,
                                              n, ppb, cnt, packed, o_F, o_m, o_J);
        k_p2g_tile<<<NTILE, PBLK, 0, stream>>>(packed, tstart, tend, gvx, gvy, gm);
        k_grid   <<<ggrid, BLOCK, 0, stream>>>(gvx, gvy, gm, gfin);
        k_g2p    <<<pgrid, BLOCK, 0, stream>>>(x, gfin, o_x, o_v, o_C, n);
    } else {
        // fallback: single grid copy + device atomics
        float* g = (float*)d_ws;                       // NCELL*3
        float2* gf = (float2*)(g + (size_t)NCELL * 3); // NCELL float2
        hipMemsetAsync(g, 0, (size_t)NCELL * 3 * sizeof(float), stream);
        fb_p2g <<<pgrid, BLOCK, 0, stream>>>(x, v, C, F, mat, Jp, Ep, nup,
                                             g, o_F, o_m, o_J, n);
        fb_grid<<<ggrid, BLOCK, 0, stream>>>(g, gf);
        k_g2p  <<<pgrid, BLOCK, 0, stream>>>(x, gf, o_x, o_v, o_C, n);
    }
}